// Round 4
// baseline (3796.148 us; speedup 1.0000x reference)
//
#include <hip/hip_runtime.h>

// DeeperGCN round 4.
// Fixes from round-3 counters: (1) mlp_kernel VGPR=88 => spilled; rebuilt with
// x staged in per-lane LDS rows (dynamic K-loop, rolled), h[128]/o2[64] static in
// registers, __launch_bounds__(256,2); weights via wave-uniform (SMEM) loads.
// (2) 260us single-block scan => 3-kernel hierarchical scan. (3) agg CSR metadata
// forced scalar via readfirstlane. (4) head gets launch-bounds fix too.

#define NN 100000
#define NE 800000
#define CH 64
#define NC (NN * CH)
#define NT 1563            // ceil(NN / 64) node tiles
#define SB 98              // scan blocks (98 * 1024 >= NN)
#define EPS_MSG 1e-7f
#define EPS_LN 1e-5f

// ---------------- counting sort: histogram ----------------
__global__ __launch_bounds__(256) void hist_kernel(const int* __restrict__ ei,
                                                   int* __restrict__ cursor) {
    int e = blockIdx.x * 256 + threadIdx.x;
    if (e < NE) atomicAdd(&cursor[ei[NE + e]], 1);
}

// ---------------- hierarchical scan: block partials ----------------
__global__ __launch_bounds__(256) void scan1_kernel(const int* __restrict__ cursor,
                                                    int* __restrict__ part) {
    __shared__ int sp[4];
    const int t = threadIdx.x;
    const int i0 = blockIdx.x * 1024 + t * 4;
    int s = 0;
    #pragma unroll
    for (int j = 0; j < 4; ++j) { int i = i0 + j; if (i < NN) s += cursor[i]; }
    #pragma unroll
    for (int o = 32; o; o >>= 1) s += __shfl_xor(s, o);
    if ((t & 63) == 0) sp[t >> 6] = s;
    __syncthreads();
    if (t == 0) part[blockIdx.x] = sp[0] + sp[1] + sp[2] + sp[3];
}

// ---------------- scan partials (exclusive) ----------------
__global__ __launch_bounds__(128) void scan2_kernel(int* __restrict__ part,
                                                    int* __restrict__ off) {
    __shared__ int sc[128];
    const int t = threadIdx.x;
    int v = (t < SB) ? part[t] : 0;
    sc[t] = v;
    __syncthreads();
    for (int o = 1; o < 128; o <<= 1) {
        int u = (t >= o) ? sc[t - o] : 0;
        __syncthreads();
        sc[t] += u;
        __syncthreads();
    }
    if (t < SB) part[t] = sc[t] - v;    // exclusive prefix
    if (t == 0) off[NN] = NE;
}

// ---------------- apply: write row pointers + cursor starts ----------------
__global__ __launch_bounds__(256) void scan3_kernel(const int* __restrict__ part,
                                                    int* __restrict__ cursor,
                                                    int* __restrict__ off) {
    __shared__ int sc[256];
    const int t = threadIdx.x;
    const int i0 = blockIdx.x * 1024 + t * 4;
    int deg[4];
    int s = 0;
    #pragma unroll
    for (int j = 0; j < 4; ++j) { int i = i0 + j; deg[j] = (i < NN) ? cursor[i] : 0; s += deg[j]; }
    sc[t] = s;
    __syncthreads();
    for (int o = 1; o < 256; o <<= 1) {
        int u = (t >= o) ? sc[t - o] : 0;
        __syncthreads();
        sc[t] += u;
        __syncthreads();
    }
    int run = part[blockIdx.x] + sc[t] - s;   // block base + thread-exclusive
    #pragma unroll
    for (int j = 0; j < 4; ++j) {
        int i = i0 + j;
        if (i < NN) { off[i] = run; cursor[i] = run; run += deg[j]; }
    }
}

// ---------------- scatter src ids grouped by dst ----------------
__global__ __launch_bounds__(256) void scatter_kernel(const int* __restrict__ ei,
                                                      int* __restrict__ cursor,
                                                      int* __restrict__ esrc) {
    int e = blockIdx.x * 256 + threadIdx.x;
    if (e >= NE) return;
    int dst = ei[NE + e];
    int pos = atomicAdd(&cursor[dst], 1);
    esrc[pos] = ei[e];
}

// ---------------- aggregation: wave per node, channel per lane ----------------
template <int MODE>
__global__ __launch_bounds__(256) void agg_kernel(
    const float* __restrict__ xin, const int* __restrict__ off,
    const int* __restrict__ esrc, const double* __restrict__ ds_in,
    const float* __restrict__ gw, const float* __restrict__ gb,
    float* __restrict__ hbuf)
{
    const int lane = threadIdx.x & 63;
    const int n = __builtin_amdgcn_readfirstlane((blockIdx.x * 256 + threadIdx.x) >> 6);
    if (n >= NN) return;
    float A = 1.f, B = 0.f;
    if (MODE) {
        double S = ds_in[0], Q = ds_in[1];
        double mud = S / (double)NC;
        float var = (float)(Q / (double)NC - mud * mud);
        float scale = 1.f / (sqrtf(fmaxf(var, 0.f)) + EPS_LN);
        A = scale * gw[lane];
        B = fmaf(-(float)mud, A, gb[lane]);
    }
    const size_t base = (size_t)n * CH + lane;
    const float xb = xin[base];
    const int p0 = off[n], p1 = off[n + 1];
    float den = 0.f, num = 0.f;
    for (int q = p0; q < p1; q += 8) {
        int m = p1 - q; if (m > 8) m = 8;
        float v[8];
        #pragma unroll
        for (int i = 0; i < 8; ++i)
            if (i < m) v[i] = xin[(size_t)esrc[q + i] * CH + lane];
        #pragma unroll
        for (int i = 0; i < 8; ++i)
            if (i < m) {
                float mm = MODE ? fmaxf(fmaf(v[i], A, B), 0.f) + EPS_MSG
                                : fmaxf(v[i], 0.f) + EPS_MSG;
                float e = __expf(mm);
                den += e;
                num = fmaf(mm, e, num);
            }
    }
    float agg = den > 0.f ? num / den : 0.f;
    float xl = MODE ? fmaxf(fmaf(xb, A, B), 0.f) : xb;
    hbuf[base] = agg + xl;
}

// ---------------- MLP: node-per-lane, x in per-lane LDS row, h/o2 in regs ----------------
// 64 -> 128 -> torchLN -> relu -> 64 (+residual in MODE 1), output stats -> ds_out.
template <int MODE>
__global__ __launch_bounds__(256, 2) void mlp_kernel(
    const float* __restrict__ hbuf, const float* __restrict__ xres,
    const float* __restrict__ W1, const float* __restrict__ b1,
    const float* __restrict__ lnw, const float* __restrict__ lnb,
    const float* __restrict__ W2, const float* __restrict__ b2,
    float* __restrict__ out, double* __restrict__ ds_out)
{
    __shared__ float xt[4][64 * 65];     // per-wave lane-indexed scratch (stride 65: conflict-free)
    __shared__ float sstat[8];
    const int lane = threadIdx.x & 63;
    const int wv = threadIdx.x >> 6;
    const int tile = blockIdx.x * 4 + wv;
    const int base0 = tile * 64;
    const bool vt = base0 < NN;
    const int base = vt ? base0 : 0;
    const int nvalid = vt ? ((NN - base < 64) ? (NN - base) : 64) : 0;
    float* xw = xt[wv];

    // stage this lane's node row into its private LDS row
    {
        const int nd = base + ((lane < nvalid) ? lane : 0);
        const float* xp = hbuf + (size_t)nd * CH;
        #pragma unroll
        for (int c4 = 0; c4 < 16; ++c4) {
            float4 v = *reinterpret_cast<const float4*>(xp + c4 * 4);
            xw[lane * 65 + c4 * 4 + 0] = v.x;
            xw[lane * 65 + c4 * 4 + 1] = v.y;
            xw[lane * 65 + c4 * 4 + 2] = v.z;
            xw[lane * 65 + c4 * 4 + 3] = v.w;
        }
    }

    // phase 1: h = b1 + x @ W1 ; c-loop rolled (dynamic), j unrolled (static regs)
    float h[128];
    #pragma unroll
    for (int j = 0; j < 128; ++j) h[j] = b1[j];
    #pragma unroll 1
    for (int c4 = 0; c4 < 16; ++c4) {
        const float xv0 = xw[lane * 65 + c4 * 4 + 0];
        const float xv1 = xw[lane * 65 + c4 * 4 + 1];
        const float xv2 = xw[lane * 65 + c4 * 4 + 2];
        const float xv3 = xw[lane * 65 + c4 * 4 + 3];
        const float* w1p = W1 + c4 * 4 * 128;   // wave-uniform -> SMEM loads
        #pragma unroll
        for (int j = 0; j < 128; ++j) h[j] = fmaf(xv0, w1p[j], h[j]);
        #pragma unroll
        for (int j = 0; j < 128; ++j) h[j] = fmaf(xv1, w1p[128 + j], h[j]);
        #pragma unroll
        for (int j = 0; j < 128; ++j) h[j] = fmaf(xv2, w1p[256 + j], h[j]);
        #pragma unroll
        for (int j = 0; j < 128; ++j) h[j] = fmaf(xv3, w1p[384 + j], h[j]);
    }

    // torch LayerNorm over 128
    float s = 0.f, sq = 0.f;
    #pragma unroll
    for (int j = 0; j < 128; ++j) { s += h[j]; sq = fmaf(h[j], h[j], sq); }
    const float mu = s * (1.f / 128.f);
    const float var = sq * (1.f / 128.f) - mu * mu;
    const float rstd = 1.f / sqrtf(var + EPS_LN);
    const float nmr = -mu * rstd;

    // phase 2: o2 = b2 + relu(ln(h)) @ W2
    float o2[64];
    #pragma unroll
    for (int c = 0; c < 64; ++c) o2[c] = b2[c];
    #pragma unroll
    for (int j = 0; j < 128; ++j) {
        const float r = fmaxf(fmaf(fmaf(h[j], rstd, nmr), lnw[j], lnb[j]), 0.f);
        const float* w2p = W2 + j * 64;
        #pragma unroll
        for (int c = 0; c < 64; ++c) o2[c] = fmaf(r, w2p[c], o2[c]);
    }

    // phase 3: transpose out via LDS in 4x16-channel chunks (wave-local), +residual, stats
    float as = 0.f, aq = 0.f;
    const int i0 = lane & 15;
    const int r0 = lane >> 4;
    #pragma unroll
    for (int cb = 0; cb < 4; ++cb) {
        #pragma unroll
        for (int i = 0; i < 16; ++i) xw[lane * 65 + i] = o2[cb * 16 + i];
        #pragma unroll
        for (int k = 0; k < 16; ++k) {
            const int r = r0 + k * 4;
            if (r < nvalid) {
                float val = xw[r * 65 + i0];
                const size_t gi = (size_t)(base + r) * CH + cb * 16 + i0;
                if (MODE) val += xres[gi];
                out[gi] = val;
                as += val;
                aq = fmaf(val, val, aq);
            }
        }
    }
    #pragma unroll
    for (int o = 32; o; o >>= 1) { as += __shfl_xor(as, o); aq += __shfl_xor(aq, o); }
    if (lane == 0) { sstat[wv] = as; sstat[4 + wv] = aq; }
    __syncthreads();
    if (threadIdx.x == 0) {
        unsafeAtomicAdd(ds_out + 0, (double)(sstat[0] + sstat[1] + sstat[2] + sstat[3]));
        unsafeAtomicAdd(ds_out + 1, (double)(sstat[4] + sstat[5] + sstat[6] + sstat[7]));
    }
}

// ---------------- layer-1 graph-LN apply (+relu) with output stats ----------------
__global__ __launch_bounds__(256) void ln_apply_kernel(
    const float* __restrict__ in, const float* __restrict__ w,
    const float* __restrict__ b, const double* __restrict__ ds_in,
    float* __restrict__ out, double* __restrict__ ds_out)
{
    __shared__ float ps[4], pq[4];
    double S = ds_in[0], Q = ds_in[1];
    double mud = S / (double)NC;
    float mu = (float)mud;
    float var = (float)(Q / (double)NC - mud * mud);
    float scale = 1.f / (sqrtf(fmaxf(var, 0.f)) + EPS_LN);
    float s = 0.f, q = 0.f;
    int idx = blockIdx.x * 256 + threadIdx.x;
    int stride = gridDim.x * 256;
    for (int i = idx; i < NC / 4; i += stride) {
        int c = (i & 15) << 2;
        float4 v = reinterpret_cast<const float4*>(in)[i];
        float4 wv = *reinterpret_cast<const float4*>(w + c);
        float4 bv = *reinterpret_cast<const float4*>(b + c);
        float4 o;
        o.x = fmaxf(fmaf((v.x - mu) * scale, wv.x, bv.x), 0.f);
        o.y = fmaxf(fmaf((v.y - mu) * scale, wv.y, bv.y), 0.f);
        o.z = fmaxf(fmaf((v.z - mu) * scale, wv.z, bv.z), 0.f);
        o.w = fmaxf(fmaf((v.w - mu) * scale, wv.w, bv.w), 0.f);
        reinterpret_cast<float4*>(out)[i] = o;
        s += (o.x + o.y) + (o.z + o.w);
        q += fmaf(o.x, o.x, o.y * o.y) + fmaf(o.z, o.z, o.w * o.w);
    }
    int lane = threadIdx.x & 63, wv2 = threadIdx.x >> 6;
    #pragma unroll
    for (int o = 32; o; o >>= 1) { s += __shfl_xor(s, o); q += __shfl_xor(q, o); }
    if (lane == 0) { ps[wv2] = s; pq[wv2] = q; }
    __syncthreads();
    if (threadIdx.x == 0) {
        unsafeAtomicAdd(ds_out + 0, (double)((ps[0] + ps[1]) + (ps[2] + ps[3])));
        unsafeAtomicAdd(ds_out + 1, (double)((pq[0] + pq[1]) + (pq[2] + pq[3])));
    }
}

// ---------------- head: node-per-lane, chunked ----------------
__global__ __launch_bounds__(256, 2) void head_kernel(
    const float* __restrict__ xc,
    const float* __restrict__ W1, const float* __restrict__ b1,
    const float* __restrict__ W2, const float* __restrict__ b2,
    const float* __restrict__ W3, const float* __restrict__ b3,
    float* __restrict__ out)
{
    const int lane = threadIdx.x & 63;
    const int tile = blockIdx.x * 4 + (threadIdx.x >> 6);
    if (tile >= NT) return;
    const int base = tile * 64;
    const int node = base + lane;
    const bool act = node < NN;
    const float* xp = xc + (size_t)(act ? node : base) * CH;
    float x[64];
    #pragma unroll
    for (int c4 = 0; c4 < 16; ++c4) {
        float4 v = *reinterpret_cast<const float4*>(xp + c4 * 4);
        x[c4 * 4 + 0] = v.x; x[c4 * 4 + 1] = v.y;
        x[c4 * 4 + 2] = v.z; x[c4 * 4 + 3] = v.w;
    }
    float y2[64];
    #pragma unroll
    for (int c = 0; c < 64; ++c) y2[c] = b2[c];
    #pragma unroll 1
    for (int jb = 0; jb < 4; ++jb) {
        float acc[16];
        #pragma unroll
        for (int i = 0; i < 16; ++i) acc[i] = b1[jb * 16 + i];
        #pragma unroll
        for (int c = 0; c < 64; ++c) {
            float xv = x[c];
            #pragma unroll
            for (int i = 0; i < 16; ++i)
                acc[i] = fmaf(xv, W1[c * 64 + jb * 16 + i], acc[i]);
        }
        #pragma unroll
        for (int i = 0; i < 16; ++i) {
            float r = fmaxf(acc[i], 0.f);
            const int j = jb * 16 + i;
            #pragma unroll
            for (int c = 0; c < 64; ++c)
                y2[c] = fmaf(r, W2[j * 64 + c], y2[c]);
        }
    }
    float p0 = b3[0], p1 = b3[1];
    #pragma unroll
    for (int c = 0; c < 64; ++c) {
        float r = fmaxf(y2[c], 0.f);
        p0 = fmaf(r, W3[c * 2 + 0], p0);
        p1 = fmaf(r, W3[c * 2 + 1], p1);
    }
    if (act) {
        float2 st; st.x = p0; st.y = p1;
        *reinterpret_cast<float2*>(out + (size_t)node * 2) = st;
    }
}

extern "C" void kernel_launch(void* const* d_in, const int* in_sizes, int n_in,
                              void* d_out, int out_size, void* d_ws, size_t ws_size,
                              hipStream_t stream)
{
    const float* x     = (const float*)d_in[0];
    const int*   ei    = (const int*)d_in[1];
    const float* c1W1  = (const float*)d_in[2];
    const float* c1b1  = (const float*)d_in[3];
    const float* c1lnw = (const float*)d_in[4];
    const float* c1lnb = (const float*)d_in[5];
    const float* c1W2  = (const float*)d_in[6];
    const float* c1b2  = (const float*)d_in[7];
    const float* n1w   = (const float*)d_in[8];
    const float* n1b   = (const float*)d_in[9];
    const float* cW1   = (const float*)d_in[10];
    const float* cb1   = (const float*)d_in[11];
    const float* clnw  = (const float*)d_in[12];
    const float* clnb  = (const float*)d_in[13];
    const float* cW2   = (const float*)d_in[14];
    const float* cb2   = (const float*)d_in[15];
    const float* nw    = (const float*)d_in[16];
    const float* nb    = (const float*)d_in[17];
    const float* lW1   = (const float*)d_in[18];
    const float* lb1   = (const float*)d_in[19];
    const float* lW2   = (const float*)d_in[20];
    const float* lb2   = (const float*)d_in[21];
    const float* lW3   = (const float*)d_in[22];
    const float* lb3   = (const float*)d_in[23];
    float* out = (float*)d_out;

    // workspace: bufA, bufB, hbuf [N,64]; cursor[NN]; off[NN+2]; esrc[NE]; part[256]; dsum f64
    float* bufA = (float*)d_ws;
    float* bufB = bufA + NC;
    float* hbuf = bufB + NC;
    int* cursor = (int*)(hbuf + NC);
    int* off    = cursor + NN;
    int* esrc   = off + NN + 2;
    int* part   = esrc + NE;
    double* dsum = (double*)(part + 256);

    hipMemsetAsync(cursor, 0, NN * sizeof(int), stream);
    hipMemsetAsync(dsum, 0, 10 * sizeof(double), stream);
    hist_kernel<<<3125, 256, 0, stream>>>(ei, cursor);
    scan1_kernel<<<SB, 256, 0, stream>>>(cursor, part);
    scan2_kernel<<<1, 128, 0, stream>>>(part, off);
    scan3_kernel<<<SB, 256, 0, stream>>>(part, cursor, off);
    scatter_kernel<<<3125, 256, 0, stream>>>(ei, cursor, esrc);

    const int AGG_BLOCKS = 25000;   // wave per node
    const int MLP_BLOCKS = 391;     // 4 tiles per block

    // layer 1 (plain)
    agg_kernel<0><<<AGG_BLOCKS, 256, 0, stream>>>(x, off, esrc, nullptr, nullptr, nullptr, hbuf);
    mlp_kernel<0><<<MLP_BLOCKS, 256, 0, stream>>>(hbuf, nullptr, c1W1, c1b1, c1lnw, c1lnb,
                                                  c1W2, c1b2, bufA, dsum + 0);
    ln_apply_kernel<<<2048, 256, 0, stream>>>(bufA, n1w, n1b, dsum + 0, bufB, dsum + 2);

    // layers 2..4 (res+), ping-pong xc between bufB/bufA
    agg_kernel<1><<<AGG_BLOCKS, 256, 0, stream>>>(bufB, off, esrc, dsum + 2, nw + 0, nb + 0, hbuf);
    mlp_kernel<1><<<MLP_BLOCKS, 256, 0, stream>>>(hbuf, bufB, cW1 + 0 * 8192, cb1 + 0 * 128,
                                                  clnw + 0 * 128, clnb + 0 * 128,
                                                  cW2 + 0 * 8192, cb2 + 0 * 64, bufA, dsum + 4);

    agg_kernel<1><<<AGG_BLOCKS, 256, 0, stream>>>(bufA, off, esrc, dsum + 4, nw + 64, nb + 64, hbuf);
    mlp_kernel<1><<<MLP_BLOCKS, 256, 0, stream>>>(hbuf, bufA, cW1 + 1 * 8192, cb1 + 1 * 128,
                                                  clnw + 1 * 128, clnb + 1 * 128,
                                                  cW2 + 1 * 8192, cb2 + 1 * 64, bufB, dsum + 6);

    agg_kernel<1><<<AGG_BLOCKS, 256, 0, stream>>>(bufB, off, esrc, dsum + 6, nw + 128, nb + 128, hbuf);
    mlp_kernel<1><<<MLP_BLOCKS, 256, 0, stream>>>(hbuf, bufB, cW1 + 2 * 8192, cb1 + 2 * 128,
                                                  clnw + 2 * 128, clnb + 2 * 128,
                                                  cW2 + 2 * 8192, cb2 + 2 * 64, bufA, dsum + 8);

    // dense head
    head_kernel<<<MLP_BLOCKS, 256, 0, stream>>>(bufA, lW1, lb1, lW2, lb2, lW3, lb3, out);
}

// Round 5
// 1256.548 us; speedup vs baseline: 3.0211x; 3.0211x over previous
//
#include <hip/hip_runtime.h>

// DeeperGCN round 5.
// Round-4 failure: mlp h[128]+o2[64] live state -> allocator capped 128 VGPR, spilled,
// 480MB scratch FETCH/dispatch. Fix: bounded-register design. x in per-lane LDS row
// (stride 65, wave-private); hidden in acc[32] chunks; phase 1 = stats only; phase 2
// recomputes chunks (identical order) folding relu(LN(h)) into persistent o2[64].
// Peak live floats ~110 -> no spill. Head rebuilt the same way.

#define NN 100000
#define NE 800000
#define CH 64
#define NC (NN * CH)
#define NT 1563            // ceil(NN / 64) node tiles
#define SB 98              // scan blocks
#define XS 65              // LDS x-row stride (conflict-free)
#define EPS_MSG 1e-7f
#define EPS_LN 1e-5f

// ---------------- counting sort: histogram ----------------
__global__ __launch_bounds__(256) void hist_kernel(const int* __restrict__ ei,
                                                   int* __restrict__ cursor) {
    int e = blockIdx.x * 256 + threadIdx.x;
    if (e < NE) atomicAdd(&cursor[ei[NE + e]], 1);
}

// ---------------- hierarchical scan ----------------
__global__ __launch_bounds__(256) void scan1_kernel(const int* __restrict__ cursor,
                                                    int* __restrict__ part) {
    __shared__ int sp[4];
    const int t = threadIdx.x;
    const int i0 = blockIdx.x * 1024 + t * 4;
    int s = 0;
    #pragma unroll
    for (int j = 0; j < 4; ++j) { int i = i0 + j; if (i < NN) s += cursor[i]; }
    #pragma unroll
    for (int o = 32; o; o >>= 1) s += __shfl_xor(s, o);
    if ((t & 63) == 0) sp[t >> 6] = s;
    __syncthreads();
    if (t == 0) part[blockIdx.x] = sp[0] + sp[1] + sp[2] + sp[3];
}

__global__ __launch_bounds__(128) void scan2_kernel(int* __restrict__ part,
                                                    int* __restrict__ off) {
    __shared__ int sc[128];
    const int t = threadIdx.x;
    int v = (t < SB) ? part[t] : 0;
    sc[t] = v;
    __syncthreads();
    for (int o = 1; o < 128; o <<= 1) {
        int u = (t >= o) ? sc[t - o] : 0;
        __syncthreads();
        sc[t] += u;
        __syncthreads();
    }
    if (t < SB) part[t] = sc[t] - v;
    if (t == 0) off[NN] = NE;
}

__global__ __launch_bounds__(256) void scan3_kernel(const int* __restrict__ part,
                                                    int* __restrict__ cursor,
                                                    int* __restrict__ off) {
    __shared__ int sc[256];
    const int t = threadIdx.x;
    const int i0 = blockIdx.x * 1024 + t * 4;
    int deg[4];
    int s = 0;
    #pragma unroll
    for (int j = 0; j < 4; ++j) { int i = i0 + j; deg[j] = (i < NN) ? cursor[i] : 0; s += deg[j]; }
    sc[t] = s;
    __syncthreads();
    for (int o = 1; o < 256; o <<= 1) {
        int u = (t >= o) ? sc[t - o] : 0;
        __syncthreads();
        sc[t] += u;
        __syncthreads();
    }
    int run = part[blockIdx.x] + sc[t] - s;
    #pragma unroll
    for (int j = 0; j < 4; ++j) {
        int i = i0 + j;
        if (i < NN) { off[i] = run; cursor[i] = run; run += deg[j]; }
    }
}

// ---------------- scatter src ids grouped by dst ----------------
__global__ __launch_bounds__(256) void scatter_kernel(const int* __restrict__ ei,
                                                      int* __restrict__ cursor,
                                                      int* __restrict__ esrc) {
    int e = blockIdx.x * 256 + threadIdx.x;
    if (e >= NE) return;
    int dst = ei[NE + e];
    int pos = atomicAdd(&cursor[dst], 1);
    esrc[pos] = ei[e];
}

// ---------------- aggregation: wave per node, channel per lane ----------------
template <int MODE>
__global__ __launch_bounds__(256) void agg_kernel(
    const float* __restrict__ xin, const int* __restrict__ off,
    const int* __restrict__ esrc, const double* __restrict__ ds_in,
    const float* __restrict__ gw, const float* __restrict__ gb,
    float* __restrict__ hbuf)
{
    const int lane = threadIdx.x & 63;
    const int n = __builtin_amdgcn_readfirstlane((blockIdx.x * 256 + threadIdx.x) >> 6);
    if (n >= NN) return;
    float A = 1.f, B = 0.f;
    if (MODE) {
        double S = ds_in[0], Q = ds_in[1];
        double mud = S / (double)NC;
        float var = (float)(Q / (double)NC - mud * mud);
        float scale = 1.f / (sqrtf(fmaxf(var, 0.f)) + EPS_LN);
        A = scale * gw[lane];
        B = fmaf(-(float)mud, A, gb[lane]);
    }
    const size_t base = (size_t)n * CH + lane;
    const float xb = xin[base];
    const int p0 = off[n], p1 = off[n + 1];
    float den = 0.f, num = 0.f;
    for (int q = p0; q < p1; q += 8) {
        int m = p1 - q; if (m > 8) m = 8;
        float v[8];
        #pragma unroll
        for (int i = 0; i < 8; ++i)
            if (i < m) v[i] = xin[(size_t)esrc[q + i] * CH + lane];
        #pragma unroll
        for (int i = 0; i < 8; ++i)
            if (i < m) {
                float mm = MODE ? fmaxf(fmaf(v[i], A, B), 0.f) + EPS_MSG
                                : fmaxf(v[i], 0.f) + EPS_MSG;
                float e = __expf(mm);
                den += e;
                num = fmaf(mm, e, num);
            }
    }
    float agg = den > 0.f ? num / den : 0.f;
    float xl = MODE ? fmaxf(fmaf(xb, A, B), 0.f) : xb;
    hbuf[base] = agg + xl;
}

// ---------------- MLP: node-per-lane, bounded registers ----------------
// 64 -> 128 -> torchLN -> relu -> 64 (+residual MODE 1), output stats -> ds_out.
// x in per-lane LDS row; hidden in acc[32] chunks; phase1 stats, phase2 recompute.
template <int MODE>
__global__ __launch_bounds__(256, 2) void mlp_kernel(
    const float* __restrict__ hbuf, const float* __restrict__ xres,
    const float* __restrict__ W1, const float* __restrict__ b1,
    const float* __restrict__ lnw, const float* __restrict__ lnb,
    const float* __restrict__ W2, const float* __restrict__ b2,
    float* __restrict__ out, double* __restrict__ ds_out)
{
    __shared__ float xt[4][64 * XS];
    __shared__ float sstat[8];
    const int lane = threadIdx.x & 63;
    const int wv = threadIdx.x >> 6;
    const int tile = blockIdx.x * 4 + wv;
    const int base0 = tile * 64;
    const bool vt = base0 < NN;
    const int base = vt ? base0 : 0;
    const int nvalid = vt ? ((NN - base < 64) ? (NN - base) : 64) : 0;
    float* xw = xt[wv];

    // stage this lane's node row into its private LDS row (wave-private; no barrier)
    {
        const int nd = base + ((lane < nvalid) ? lane : 0);
        const float* xp = hbuf + (size_t)nd * CH;
        #pragma unroll
        for (int c4 = 0; c4 < 16; ++c4) {
            float4 v = *reinterpret_cast<const float4*>(xp + c4 * 4);
            xw[lane * XS + c4 * 4 + 0] = v.x;
            xw[lane * XS + c4 * 4 + 1] = v.y;
            xw[lane * XS + c4 * 4 + 2] = v.z;
            xw[lane * XS + c4 * 4 + 3] = v.w;
        }
    }

    // phase 1: hidden stats in chunks of 32
    float s = 0.f, sq = 0.f;
    #pragma unroll 1
    for (int jb = 0; jb < 4; ++jb) {
        float acc[32];
        const float* b1p = b1 + jb * 32;
        #pragma unroll
        for (int i = 0; i < 32; ++i) acc[i] = b1p[i];
        #pragma unroll 1
        for (int c = 0; c < 64; ++c) {
            const float xv = xw[lane * XS + c];
            const float* w1p = W1 + c * 128 + jb * 32;   // wave-uniform -> SMEM
            #pragma unroll
            for (int i = 0; i < 32; ++i) acc[i] = fmaf(xv, w1p[i], acc[i]);
        }
        #pragma unroll
        for (int i = 0; i < 32; ++i) { s += acc[i]; sq = fmaf(acc[i], acc[i], sq); }
    }
    const float mu = s * (1.f / 128.f);
    const float var = sq * (1.f / 128.f) - mu * mu;
    const float rstd = 1.f / sqrtf(var + EPS_LN);
    const float nmr = -mu * rstd;

    // phase 2: recompute chunks (identical order), fold relu(LN(h)) into o2[64]
    float o2[64];
    #pragma unroll
    for (int c = 0; c < 64; ++c) o2[c] = b2[c];
    #pragma unroll 1
    for (int jb = 0; jb < 4; ++jb) {
        float acc[32];
        const float* b1p = b1 + jb * 32;
        #pragma unroll
        for (int i = 0; i < 32; ++i) acc[i] = b1p[i];
        #pragma unroll 1
        for (int c = 0; c < 64; ++c) {
            const float xv = xw[lane * XS + c];
            const float* w1p = W1 + c * 128 + jb * 32;
            #pragma unroll
            for (int i = 0; i < 32; ++i) acc[i] = fmaf(xv, w1p[i], acc[i]);
        }
        const float* lnwp = lnw + jb * 32;
        const float* lnbp = lnb + jb * 32;
        const float* w2b = W2 + jb * 32 * 64;
        #pragma unroll
        for (int i = 0; i < 32; ++i) {
            const float r = fmaxf(fmaf(fmaf(acc[i], rstd, nmr), lnwp[i], lnbp[i]), 0.f);
            const float* w2p = w2b + i * 64;
            #pragma unroll
            for (int c = 0; c < 64; ++c) o2[c] = fmaf(r, w2p[c], o2[c]);
        }
    }

    // phase 3: transpose out via the (now free) LDS x area, +residual, stats
    float as = 0.f, aq = 0.f;
    const int i0 = lane & 15;
    const int r0 = lane >> 4;
    #pragma unroll 1
    for (int cb = 0; cb < 4; ++cb) {
        #pragma unroll
        for (int i = 0; i < 16; ++i) xw[lane * XS + i] = o2[cb * 16 + i];
        #pragma unroll
        for (int k = 0; k < 16; ++k) {
            const int r = r0 + k * 4;
            if (r < nvalid) {
                float val = xw[r * XS + i0];
                const size_t gi = (size_t)(base + r) * CH + cb * 16 + i0;
                if (MODE) val += xres[gi];
                out[gi] = val;
                as += val;
                aq = fmaf(val, val, aq);
            }
        }
    }
    #pragma unroll
    for (int o = 32; o; o >>= 1) { as += __shfl_xor(as, o); aq += __shfl_xor(aq, o); }
    if (lane == 0) { sstat[wv] = as; sstat[4 + wv] = aq; }
    __syncthreads();
    if (threadIdx.x == 0) {
        unsafeAtomicAdd(ds_out + 0, (double)(sstat[0] + sstat[1] + sstat[2] + sstat[3]));
        unsafeAtomicAdd(ds_out + 1, (double)(sstat[4] + sstat[5] + sstat[6] + sstat[7]));
    }
}

// ---------------- layer-1 graph-LN apply (+relu) with output stats ----------------
__global__ __launch_bounds__(256) void ln_apply_kernel(
    const float* __restrict__ in, const float* __restrict__ w,
    const float* __restrict__ b, const double* __restrict__ ds_in,
    float* __restrict__ out, double* __restrict__ ds_out)
{
    __shared__ float ps[4], pq[4];
    double S = ds_in[0], Q = ds_in[1];
    double mud = S / (double)NC;
    float mu = (float)mud;
    float var = (float)(Q / (double)NC - mud * mud);
    float scale = 1.f / (sqrtf(fmaxf(var, 0.f)) + EPS_LN);
    float s = 0.f, q = 0.f;
    int idx = blockIdx.x * 256 + threadIdx.x;
    int stride = gridDim.x * 256;
    for (int i = idx; i < NC / 4; i += stride) {
        int c = (i & 15) << 2;
        float4 v = reinterpret_cast<const float4*>(in)[i];
        float4 wv = *reinterpret_cast<const float4*>(w + c);
        float4 bv = *reinterpret_cast<const float4*>(b + c);
        float4 o;
        o.x = fmaxf(fmaf((v.x - mu) * scale, wv.x, bv.x), 0.f);
        o.y = fmaxf(fmaf((v.y - mu) * scale, wv.y, bv.y), 0.f);
        o.z = fmaxf(fmaf((v.z - mu) * scale, wv.z, bv.z), 0.f);
        o.w = fmaxf(fmaf((v.w - mu) * scale, wv.w, bv.w), 0.f);
        reinterpret_cast<float4*>(out)[i] = o;
        s += (o.x + o.y) + (o.z + o.w);
        q += fmaf(o.x, o.x, o.y * o.y) + fmaf(o.z, o.z, o.w * o.w);
    }
    int lane = threadIdx.x & 63, wv2 = threadIdx.x >> 6;
    #pragma unroll
    for (int o = 32; o; o >>= 1) { s += __shfl_xor(s, o); q += __shfl_xor(q, o); }
    if (lane == 0) { ps[wv2] = s; pq[wv2] = q; }
    __syncthreads();
    if (threadIdx.x == 0) {
        unsafeAtomicAdd(ds_out + 0, (double)((ps[0] + ps[1]) + (ps[2] + ps[3])));
        unsafeAtomicAdd(ds_out + 1, (double)((pq[0] + pq[1]) + (pq[2] + pq[3])));
    }
}

// ---------------- head: node-per-lane, bounded registers ----------------
__global__ __launch_bounds__(256, 2) void head_kernel(
    const float* __restrict__ xc,
    const float* __restrict__ W1, const float* __restrict__ b1,
    const float* __restrict__ W2, const float* __restrict__ b2,
    const float* __restrict__ W3, const float* __restrict__ b3,
    float* __restrict__ out)
{
    __shared__ float xt[4][64 * XS];
    const int lane = threadIdx.x & 63;
    const int wv = threadIdx.x >> 6;
    const int tile = blockIdx.x * 4 + wv;
    if (tile >= NT) return;                 // no barriers below: safe
    const int base = tile * 64;
    const int node = base + lane;
    const bool act = node < NN;
    float* xw = xt[wv];
    {
        const float* xp = xc + (size_t)(act ? node : base) * CH;
        #pragma unroll
        for (int c4 = 0; c4 < 16; ++c4) {
            float4 v = *reinterpret_cast<const float4*>(xp + c4 * 4);
            xw[lane * XS + c4 * 4 + 0] = v.x;
            xw[lane * XS + c4 * 4 + 1] = v.y;
            xw[lane * XS + c4 * 4 + 2] = v.z;
            xw[lane * XS + c4 * 4 + 3] = v.w;
        }
    }
    float y2[64];
    #pragma unroll
    for (int c = 0; c < 64; ++c) y2[c] = b2[c];
    #pragma unroll 1
    for (int jb = 0; jb < 4; ++jb) {
        float acc[16];
        const float* b1p = b1 + jb * 16;
        #pragma unroll
        for (int i = 0; i < 16; ++i) acc[i] = b1p[i];
        #pragma unroll 1
        for (int c = 0; c < 64; ++c) {
            const float xv = xw[lane * XS + c];
            const float* w1p = W1 + c * 64 + jb * 16;
            #pragma unroll
            for (int i = 0; i < 16; ++i) acc[i] = fmaf(xv, w1p[i], acc[i]);
        }
        const float* w2b = W2 + jb * 16 * 64;
        #pragma unroll
        for (int i = 0; i < 16; ++i) {
            const float r = fmaxf(acc[i], 0.f);
            const float* w2p = w2b + i * 64;
            #pragma unroll
            for (int c = 0; c < 64; ++c) y2[c] = fmaf(r, w2p[c], y2[c]);
        }
    }
    float p0 = b3[0], p1 = b3[1];
    #pragma unroll
    for (int c = 0; c < 64; ++c) {
        const float r = fmaxf(y2[c], 0.f);
        p0 = fmaf(r, W3[c * 2 + 0], p0);
        p1 = fmaf(r, W3[c * 2 + 1], p1);
    }
    if (act) {
        float2 st; st.x = p0; st.y = p1;
        *reinterpret_cast<float2*>(out + (size_t)node * 2) = st;
    }
}

extern "C" void kernel_launch(void* const* d_in, const int* in_sizes, int n_in,
                              void* d_out, int out_size, void* d_ws, size_t ws_size,
                              hipStream_t stream)
{
    const float* x     = (const float*)d_in[0];
    const int*   ei    = (const int*)d_in[1];
    const float* c1W1  = (const float*)d_in[2];
    const float* c1b1  = (const float*)d_in[3];
    const float* c1lnw = (const float*)d_in[4];
    const float* c1lnb = (const float*)d_in[5];
    const float* c1W2  = (const float*)d_in[6];
    const float* c1b2  = (const float*)d_in[7];
    const float* n1w   = (const float*)d_in[8];
    const float* n1b   = (const float*)d_in[9];
    const float* cW1   = (const float*)d_in[10];
    const float* cb1   = (const float*)d_in[11];
    const float* clnw  = (const float*)d_in[12];
    const float* clnb  = (const float*)d_in[13];
    const float* cW2   = (const float*)d_in[14];
    const float* cb2   = (const float*)d_in[15];
    const float* nw    = (const float*)d_in[16];
    const float* nb    = (const float*)d_in[17];
    const float* lW1   = (const float*)d_in[18];
    const float* lb1   = (const float*)d_in[19];
    const float* lW2   = (const float*)d_in[20];
    const float* lb2   = (const float*)d_in[21];
    const float* lW3   = (const float*)d_in[22];
    const float* lb3   = (const float*)d_in[23];
    float* out = (float*)d_out;

    float* bufA = (float*)d_ws;
    float* bufB = bufA + NC;
    float* hbuf = bufB + NC;
    int* cursor = (int*)(hbuf + NC);
    int* off    = cursor + NN;
    int* esrc   = off + NN + 2;
    int* part   = esrc + NE;
    double* dsum = (double*)(part + 256);

    hipMemsetAsync(cursor, 0, NN * sizeof(int), stream);
    hipMemsetAsync(dsum, 0, 10 * sizeof(double), stream);
    hist_kernel<<<3125, 256, 0, stream>>>(ei, cursor);
    scan1_kernel<<<SB, 256, 0, stream>>>(cursor, part);
    scan2_kernel<<<1, 128, 0, stream>>>(part, off);
    scan3_kernel<<<SB, 256, 0, stream>>>(part, cursor, off);
    scatter_kernel<<<3125, 256, 0, stream>>>(ei, cursor, esrc);

    const int AGG_BLOCKS = 25000;   // wave per node
    const int MLP_BLOCKS = 391;     // 4 tiles per block

    // layer 1 (plain)
    agg_kernel<0><<<AGG_BLOCKS, 256, 0, stream>>>(x, off, esrc, nullptr, nullptr, nullptr, hbuf);
    mlp_kernel<0><<<MLP_BLOCKS, 256, 0, stream>>>(hbuf, nullptr, c1W1, c1b1, c1lnw, c1lnb,
                                                  c1W2, c1b2, bufA, dsum + 0);
    ln_apply_kernel<<<2048, 256, 0, stream>>>(bufA, n1w, n1b, dsum + 0, bufB, dsum + 2);

    // layers 2..4 (res+), ping-pong xc between bufB/bufA
    agg_kernel<1><<<AGG_BLOCKS, 256, 0, stream>>>(bufB, off, esrc, dsum + 2, nw + 0, nb + 0, hbuf);
    mlp_kernel<1><<<MLP_BLOCKS, 256, 0, stream>>>(hbuf, bufB, cW1 + 0 * 8192, cb1 + 0 * 128,
                                                  clnw + 0 * 128, clnb + 0 * 128,
                                                  cW2 + 0 * 8192, cb2 + 0 * 64, bufA, dsum + 4);

    agg_kernel<1><<<AGG_BLOCKS, 256, 0, stream>>>(bufA, off, esrc, dsum + 4, nw + 64, nb + 64, hbuf);
    mlp_kernel<1><<<MLP_BLOCKS, 256, 0, stream>>>(hbuf, bufA, cW1 + 1 * 8192, cb1 + 1 * 128,
                                                  clnw + 1 * 128, clnb + 1 * 128,
                                                  cW2 + 1 * 8192, cb2 + 1 * 64, bufB, dsum + 6);

    agg_kernel<1><<<AGG_BLOCKS, 256, 0, stream>>>(bufB, off, esrc, dsum + 6, nw + 128, nb + 128, hbuf);
    mlp_kernel<1><<<MLP_BLOCKS, 256, 0, stream>>>(hbuf, bufB, cW1 + 2 * 8192, cb1 + 2 * 128,
                                                  clnw + 2 * 128, clnb + 2 * 128,
                                                  cW2 + 2 * 8192, cb2 + 2 * 64, bufA, dsum + 8);

    // dense head
    head_kernel<<<MLP_BLOCKS, 256, 0, stream>>>(bufA, lW1, lb1, lW2, lb2, lW3, lb3, out);
}

// Round 6
// 708.170 us; speedup vs baseline: 5.3605x; 1.7744x over previous
//
#include <hip/hip_runtime.h>

// DeeperGCN round 6.
// Rounds 3-5 lesson: node-per-lane MLP (100+ live floats/lane) always spills
// (r5: VGPR=88, WRITE 142MB vs 26MB logical = acc[] spill writeback). Rebuild MLP as
// block-tiled GEMM: 256 thr / 64-node tile; X+W1 in LDS (51.2KB, 3 blocks/CU);
// acc[4][8] for H=X@W1; row-LN via shfl (threads own whole rows); H' -> same LDS;
// acc2[4][4] for O=H'@W2 (W2 global, L1-resident). Both GEMMs + LN + relu +
// residual + stats in ONE kernel, <=60 live floats/thread.

#define NN 100000
#define NE 800000
#define CH 64
#define NC (NN * CH)
#define H1 128
#define NT 1563            // ceil(NN / 64) node tiles
#define SB 98              // scan blocks
#define EPS_MSG 1e-7f
#define EPS_LN 1e-5f

// ---------------- counting sort: histogram ----------------
__global__ __launch_bounds__(256) void hist_kernel(const int* __restrict__ ei,
                                                   int* __restrict__ cursor) {
    int e = blockIdx.x * 256 + threadIdx.x;
    if (e < NE) atomicAdd(&cursor[ei[NE + e]], 1);
}

// ---------------- hierarchical scan ----------------
__global__ __launch_bounds__(256) void scan1_kernel(const int* __restrict__ cursor,
                                                    int* __restrict__ part) {
    __shared__ int sp[4];
    const int t = threadIdx.x;
    const int i0 = blockIdx.x * 1024 + t * 4;
    int s = 0;
    #pragma unroll
    for (int j = 0; j < 4; ++j) { int i = i0 + j; if (i < NN) s += cursor[i]; }
    #pragma unroll
    for (int o = 32; o; o >>= 1) s += __shfl_xor(s, o);
    if ((t & 63) == 0) sp[t >> 6] = s;
    __syncthreads();
    if (t == 0) part[blockIdx.x] = sp[0] + sp[1] + sp[2] + sp[3];
}

__global__ __launch_bounds__(128) void scan2_kernel(int* __restrict__ part,
                                                    int* __restrict__ off) {
    __shared__ int sc[128];
    const int t = threadIdx.x;
    int v = (t < SB) ? part[t] : 0;
    sc[t] = v;
    __syncthreads();
    for (int o = 1; o < 128; o <<= 1) {
        int u = (t >= o) ? sc[t - o] : 0;
        __syncthreads();
        sc[t] += u;
        __syncthreads();
    }
    if (t < SB) part[t] = sc[t] - v;
    if (t == 0) off[NN] = NE;
}

__global__ __launch_bounds__(256) void scan3_kernel(const int* __restrict__ part,
                                                    int* __restrict__ cursor,
                                                    int* __restrict__ off) {
    __shared__ int sc[256];
    const int t = threadIdx.x;
    const int i0 = blockIdx.x * 1024 + t * 4;
    int deg[4];
    int s = 0;
    #pragma unroll
    for (int j = 0; j < 4; ++j) { int i = i0 + j; deg[j] = (i < NN) ? cursor[i] : 0; s += deg[j]; }
    sc[t] = s;
    __syncthreads();
    for (int o = 1; o < 256; o <<= 1) {
        int u = (t >= o) ? sc[t - o] : 0;
        __syncthreads();
        sc[t] += u;
        __syncthreads();
    }
    int run = part[blockIdx.x] + sc[t] - s;
    #pragma unroll
    for (int j = 0; j < 4; ++j) {
        int i = i0 + j;
        if (i < NN) { off[i] = run; cursor[i] = run; run += deg[j]; }
    }
}

// ---------------- scatter src ids grouped by dst ----------------
__global__ __launch_bounds__(256) void scatter_kernel(const int* __restrict__ ei,
                                                      int* __restrict__ cursor,
                                                      int* __restrict__ esrc) {
    int e = blockIdx.x * 256 + threadIdx.x;
    if (e >= NE) return;
    int dst = ei[NE + e];
    int pos = atomicAdd(&cursor[dst], 1);
    esrc[pos] = ei[e];
}

// ---------------- aggregation: wave per node, channel per lane ----------------
template <int MODE>
__global__ __launch_bounds__(256) void agg_kernel(
    const float* __restrict__ xin, const int* __restrict__ off,
    const int* __restrict__ esrc, const double* __restrict__ ds_in,
    const float* __restrict__ gw, const float* __restrict__ gb,
    float* __restrict__ hbuf)
{
    const int lane = threadIdx.x & 63;
    const int n = __builtin_amdgcn_readfirstlane((blockIdx.x * 256 + threadIdx.x) >> 6);
    if (n >= NN) return;
    float A = 1.f, B = 0.f;
    if (MODE) {
        double S = ds_in[0], Q = ds_in[1];
        double mud = S / (double)NC;
        float var = (float)(Q / (double)NC - mud * mud);
        float scale = 1.f / (sqrtf(fmaxf(var, 0.f)) + EPS_LN);
        A = scale * gw[lane];
        B = fmaf(-(float)mud, A, gb[lane]);
    }
    const size_t base = (size_t)n * CH + lane;
    const float xb = xin[base];
    const int p0 = off[n], p1 = off[n + 1];
    float den = 0.f, num = 0.f;
    for (int q = p0; q < p1; q += 8) {
        int m = p1 - q; if (m > 8) m = 8;
        float v[8];
        #pragma unroll
        for (int i = 0; i < 8; ++i)
            if (i < m) v[i] = xin[(size_t)esrc[q + i] * CH + lane];
        #pragma unroll
        for (int i = 0; i < 8; ++i)
            if (i < m) {
                float mm = MODE ? fmaxf(fmaf(v[i], A, B), 0.f) + EPS_MSG
                                : fmaxf(v[i], 0.f) + EPS_MSG;
                float e = __expf(mm);
                den += e;
                num = fmaf(mm, e, num);
            }
    }
    float agg = den > 0.f ? num / den : 0.f;
    float xl = MODE ? fmaxf(fmaf(xb, A, B), 0.f) : xb;
    hbuf[base] = agg + xl;
}

// ---------------- fused conv MLP: block-tiled double GEMM ----------------
// 64-node tile/block. Phase A: H = X@W1+b1 (acc[4][8]); row-LN+relu via shfl;
// Phase B: O = H'@W2+b2 (acc2[4][4], W2 from global/L1) + residual + stats.
template <int MODE>
__global__ __launch_bounds__(256) void conv_mlp_kernel(
    const float* __restrict__ hbuf, const float* __restrict__ xres,
    const float* __restrict__ W1, const float* __restrict__ b1,
    const float* __restrict__ lnw, const float* __restrict__ lnb,
    const float* __restrict__ W2, const float* __restrict__ b2,
    float* __restrict__ out, double* __restrict__ ds_out)
{
    __shared__ float smem[12800];       // 51.2 KB: [X 64x68 | W1 64x132] -> reuse as H' 64x132
    __shared__ float sstat[8];
    float* xs = smem;                   // [64][68]
    float* ws = smem + 4352;            // [64][132]
    float* hs = smem;                   // [64][132] (phase B)
    const int t = threadIdx.x;
    const int base = blockIdx.x * 64;
    const int nvalid = (NN - base < 64) ? (NN - base) : 64;

    // stage X tile (row-clamped) and W1
    #pragma unroll
    for (int j = 0; j < 4; ++j) {
        const int idx = j * 256 + t;            // 1024 float4s, 16 per row
        const int r = idx >> 4;
        const int c = (idx & 15) * 4;
        const int rn = (r < nvalid) ? r : (nvalid - 1);
        const float4 v = *reinterpret_cast<const float4*>(hbuf + (size_t)(base + rn) * CH + c);
        *reinterpret_cast<float4*>(xs + r * 68 + c) = v;
    }
    #pragma unroll
    for (int j = 0; j < 8; ++j) {
        const int idx = j * 256 + t;            // 2048 float4s, 32 per row
        const int r = idx >> 5;
        const int c = (idx & 31) * 4;
        const float4 v = *reinterpret_cast<const float4*>(W1 + r * H1 + c);
        *reinterpret_cast<float4*>(ws + r * 132 + c) = v;
    }
    __syncthreads();

    const int tx = t & 15, ty = t >> 4;
    const int r0 = ty * 4;              // 4 node-rows
    const int j0 = tx * 8;              // 8 hidden cols

    // phase A: acc[i][j] = sum_k x[r0+i][k] * w1[k][j0+j]
    float acc[4][8];
    #pragma unroll
    for (int i = 0; i < 4; ++i)
        #pragma unroll
        for (int j = 0; j < 8; ++j) acc[i][j] = 0.f;
    for (int k = 0; k < 64; k += 4) {
        float av[4][4];
        #pragma unroll
        for (int i = 0; i < 4; ++i) {
            const float4 v = *reinterpret_cast<const float4*>(xs + (r0 + i) * 68 + k);
            av[i][0] = v.x; av[i][1] = v.y; av[i][2] = v.z; av[i][3] = v.w;
        }
        #pragma unroll
        for (int kk = 0; kk < 4; ++kk) {
            const float4 b0 = *reinterpret_cast<const float4*>(ws + (k + kk) * 132 + j0);
            const float4 b1f = *reinterpret_cast<const float4*>(ws + (k + kk) * 132 + j0 + 4);
            const float bv[8] = {b0.x, b0.y, b0.z, b0.w, b1f.x, b1f.y, b1f.z, b1f.w};
            #pragma unroll
            for (int i = 0; i < 4; ++i)
                #pragma unroll
                for (int j = 0; j < 8; ++j)
                    acc[i][j] = fmaf(av[i][kk], bv[j], acc[i][j]);
        }
    }

    // + b1, then per-row LayerNorm stats (row = 128 cols spread over 16 tx lanes)
    {
        const float4 bb0 = *reinterpret_cast<const float4*>(b1 + j0);
        const float4 bb1 = *reinterpret_cast<const float4*>(b1 + j0 + 4);
        const float bj[8] = {bb0.x, bb0.y, bb0.z, bb0.w, bb1.x, bb1.y, bb1.z, bb1.w};
        #pragma unroll
        for (int i = 0; i < 4; ++i)
            #pragma unroll
            for (int j = 0; j < 8; ++j) acc[i][j] += bj[j];
    }
    float rs[4], rq[4];
    #pragma unroll
    for (int i = 0; i < 4; ++i) {
        float s = 0.f, q = 0.f;
        #pragma unroll
        for (int j = 0; j < 8; ++j) { s += acc[i][j]; q = fmaf(acc[i][j], acc[i][j], q); }
        rs[i] = s; rq[i] = q;
    }
    #pragma unroll
    for (int o = 1; o <= 8; o <<= 1) {
        #pragma unroll
        for (int i = 0; i < 4; ++i) {
            rs[i] += __shfl_xor(rs[i], o);
            rq[i] += __shfl_xor(rq[i], o);
        }
    }
    // normalize + affine + relu -> H'
    {
        const float4 g0 = *reinterpret_cast<const float4*>(lnw + j0);
        const float4 g1 = *reinterpret_cast<const float4*>(lnw + j0 + 4);
        const float4 c0 = *reinterpret_cast<const float4*>(lnb + j0);
        const float4 c1 = *reinterpret_cast<const float4*>(lnb + j0 + 4);
        const float gj[8] = {g0.x, g0.y, g0.z, g0.w, g1.x, g1.y, g1.z, g1.w};
        const float cj[8] = {c0.x, c0.y, c0.z, c0.w, c1.x, c1.y, c1.z, c1.w};
        #pragma unroll
        for (int i = 0; i < 4; ++i) {
            const float mu = rs[i] * (1.f / 128.f);
            const float var = rq[i] * (1.f / 128.f) - mu * mu;
            const float rstd = 1.f / sqrtf(var + EPS_LN);
            #pragma unroll
            for (int j = 0; j < 8; ++j)
                acc[i][j] = fmaxf(fmaf((acc[i][j] - mu) * rstd, gj[j], cj[j]), 0.f);
        }
    }
    __syncthreads();                    // everyone done reading xs/ws
    #pragma unroll
    for (int i = 0; i < 4; ++i) {
        float4 v0, v1;
        v0.x = acc[i][0]; v0.y = acc[i][1]; v0.z = acc[i][2]; v0.w = acc[i][3];
        v1.x = acc[i][4]; v1.y = acc[i][5]; v1.z = acc[i][6]; v1.w = acc[i][7];
        *reinterpret_cast<float4*>(hs + (r0 + i) * 132 + j0) = v0;
        *reinterpret_cast<float4*>(hs + (r0 + i) * 132 + j0 + 4) = v1;
    }
    __syncthreads();

    // phase B: O = H' @ W2 + b2 ; acc2[4][4]; W2 rows from global (L1-resident)
    const int j2 = tx * 4;
    float acc2[4][4];
    #pragma unroll
    for (int i = 0; i < 4; ++i)
        #pragma unroll
        for (int j = 0; j < 4; ++j) acc2[i][j] = 0.f;
    for (int k = 0; k < 128; k += 4) {
        float av[4][4];
        #pragma unroll
        for (int i = 0; i < 4; ++i) {
            const float4 v = *reinterpret_cast<const float4*>(hs + (r0 + i) * 132 + k);
            av[i][0] = v.x; av[i][1] = v.y; av[i][2] = v.z; av[i][3] = v.w;
        }
        #pragma unroll
        for (int kk = 0; kk < 4; ++kk) {
            const float4 w = *reinterpret_cast<const float4*>(W2 + (k + kk) * CH + j2);
            const float wv[4] = {w.x, w.y, w.z, w.w};
            #pragma unroll
            for (int i = 0; i < 4; ++i)
                #pragma unroll
                for (int j = 0; j < 4; ++j)
                    acc2[i][j] = fmaf(av[i][kk], wv[j], acc2[i][j]);
        }
    }

    // epilogue: +b2, +residual, store, stats
    const float4 b2v = *reinterpret_cast<const float4*>(b2 + j2);
    const float bj2[4] = {b2v.x, b2v.y, b2v.z, b2v.w};
    float as = 0.f, aq = 0.f;
    #pragma unroll
    for (int i = 0; i < 4; ++i) {
        const int r = r0 + i;
        if (r < nvalid) {
            float v0 = acc2[i][0] + bj2[0];
            float v1 = acc2[i][1] + bj2[1];
            float v2 = acc2[i][2] + bj2[2];
            float v3 = acc2[i][3] + bj2[3];
            const size_t gi = (size_t)(base + r) * CH + j2;
            if (MODE) {
                const float4 xr = *reinterpret_cast<const float4*>(xres + gi);
                v0 += xr.x; v1 += xr.y; v2 += xr.z; v3 += xr.w;
            }
            float4 st; st.x = v0; st.y = v1; st.z = v2; st.w = v3;
            *reinterpret_cast<float4*>(out + gi) = st;
            as += (v0 + v1) + (v2 + v3);
            aq += fmaf(v0, v0, v1 * v1) + fmaf(v2, v2, v3 * v3);
        }
    }
    #pragma unroll
    for (int o = 32; o; o >>= 1) { as += __shfl_xor(as, o); aq += __shfl_xor(aq, o); }
    const int lane = t & 63, wv2 = t >> 6;
    if (lane == 0) { sstat[wv2] = as; sstat[4 + wv2] = aq; }
    __syncthreads();
    if (t == 0) {
        unsafeAtomicAdd(ds_out + 0, (double)(sstat[0] + sstat[1] + sstat[2] + sstat[3]));
        unsafeAtomicAdd(ds_out + 1, (double)(sstat[4] + sstat[5] + sstat[6] + sstat[7]));
    }
}

// ---------------- layer-1 graph-LN apply (+relu) with output stats ----------------
__global__ __launch_bounds__(256) void ln_apply_kernel(
    const float* __restrict__ in, const float* __restrict__ w,
    const float* __restrict__ b, const double* __restrict__ ds_in,
    float* __restrict__ out, double* __restrict__ ds_out)
{
    __shared__ float ps[4], pq[4];
    double S = ds_in[0], Q = ds_in[1];
    double mud = S / (double)NC;
    float mu = (float)mud;
    float var = (float)(Q / (double)NC - mud * mud);
    float scale = 1.f / (sqrtf(fmaxf(var, 0.f)) + EPS_LN);
    float s = 0.f, q = 0.f;
    int idx = blockIdx.x * 256 + threadIdx.x;
    int stride = gridDim.x * 256;
    for (int i = idx; i < NC / 4; i += stride) {
        int c = (i & 15) << 2;
        float4 v = reinterpret_cast<const float4*>(in)[i];
        float4 wv = *reinterpret_cast<const float4*>(w + c);
        float4 bv = *reinterpret_cast<const float4*>(b + c);
        float4 o;
        o.x = fmaxf(fmaf((v.x - mu) * scale, wv.x, bv.x), 0.f);
        o.y = fmaxf(fmaf((v.y - mu) * scale, wv.y, bv.y), 0.f);
        o.z = fmaxf(fmaf((v.z - mu) * scale, wv.z, bv.z), 0.f);
        o.w = fmaxf(fmaf((v.w - mu) * scale, wv.w, bv.w), 0.f);
        reinterpret_cast<float4*>(out)[i] = o;
        s += (o.x + o.y) + (o.z + o.w);
        q += fmaf(o.x, o.x, o.y * o.y) + fmaf(o.z, o.z, o.w * o.w);
    }
    int lane = threadIdx.x & 63, wv2 = threadIdx.x >> 6;
    #pragma unroll
    for (int o = 32; o; o >>= 1) { s += __shfl_xor(s, o); q += __shfl_xor(q, o); }
    if (lane == 0) { ps[wv2] = s; pq[wv2] = q; }
    __syncthreads();
    if (threadIdx.x == 0) {
        unsafeAtomicAdd(ds_out + 0, (double)((ps[0] + ps[1]) + (ps[2] + ps[3])));
        unsafeAtomicAdd(ds_out + 1, (double)((pq[0] + pq[1]) + (pq[2] + pq[3])));
    }
}

// ---------------- head: block-tiled GEMMs, same structure ----------------
// X[64t x 64] @ lW1 relu @ lW2 relu @ lW3 -> [64t x 2]
__global__ __launch_bounds__(256) void head_kernel(
    const float* __restrict__ xc,
    const float* __restrict__ W1, const float* __restrict__ b1,
    const float* __restrict__ W2, const float* __restrict__ b2,
    const float* __restrict__ W3, const float* __restrict__ b3,
    float* __restrict__ out)
{
    __shared__ float smem[8704];        // 34.8 KB: [X|Y 64x68] + [W 64x68]
    float* xs = smem;                   // [64][68]
    float* ws = smem + 4352;            // [64][68]
    const int t = threadIdx.x;
    const int base = blockIdx.x * 64;
    const int nvalid = (NN - base < 64) ? (NN - base) : 64;
    const int tx = t & 15, ty = t >> 4;
    const int r0 = ty * 4, j2 = tx * 4;

    #pragma unroll
    for (int j = 0; j < 4; ++j) {
        const int idx = j * 256 + t;
        const int r = idx >> 4;
        const int c = (idx & 15) * 4;
        const int rn = (r < nvalid) ? r : (nvalid - 1);
        *reinterpret_cast<float4*>(xs + r * 68 + c) =
            *reinterpret_cast<const float4*>(xc + (size_t)(base + rn) * CH + c);
        *reinterpret_cast<float4*>(ws + r * 68 + c) =
            *reinterpret_cast<const float4*>(W1 + r * CH + c);
    }
    __syncthreads();

    // layer 1: y = relu(x@W1 + b1), acc[4][4]
    float acc[4][4];
    #pragma unroll
    for (int i = 0; i < 4; ++i)
        #pragma unroll
        for (int j = 0; j < 4; ++j) acc[i][j] = 0.f;
    for (int k = 0; k < 64; k += 4) {
        float av[4][4];
        #pragma unroll
        for (int i = 0; i < 4; ++i) {
            const float4 v = *reinterpret_cast<const float4*>(xs + (r0 + i) * 68 + k);
            av[i][0] = v.x; av[i][1] = v.y; av[i][2] = v.z; av[i][3] = v.w;
        }
        #pragma unroll
        for (int kk = 0; kk < 4; ++kk) {
            const float4 w = *reinterpret_cast<const float4*>(ws + (k + kk) * 68 + j2);
            const float wv[4] = {w.x, w.y, w.z, w.w};
            #pragma unroll
            for (int i = 0; i < 4; ++i)
                #pragma unroll
                for (int j = 0; j < 4; ++j)
                    acc[i][j] = fmaf(av[i][kk], wv[j], acc[i][j]);
        }
    }
    const float4 bb = *reinterpret_cast<const float4*>(b1 + j2);
    __syncthreads();                    // done reading xs for layer 1
    #pragma unroll
    for (int i = 0; i < 4; ++i) {
        float4 v;
        v.x = fmaxf(acc[i][0] + bb.x, 0.f);
        v.y = fmaxf(acc[i][1] + bb.y, 0.f);
        v.z = fmaxf(acc[i][2] + bb.z, 0.f);
        v.w = fmaxf(acc[i][3] + bb.w, 0.f);
        *reinterpret_cast<float4*>(xs + (r0 + i) * 68 + j2) = v;   // y1 -> xs
    }
    __syncthreads();
    // stage W2
    #pragma unroll
    for (int j = 0; j < 4; ++j) {
        const int idx = j * 256 + t;
        const int r = idx >> 4;
        const int c = (idx & 15) * 4;
        *reinterpret_cast<float4*>(ws + r * 68 + c) =
            *reinterpret_cast<const float4*>(W2 + r * CH + c);
    }
    __syncthreads();

    // layer 2: y2 = relu(y1@W2 + b2)
    float acc2[4][4];
    #pragma unroll
    for (int i = 0; i < 4; ++i)
        #pragma unroll
        for (int j = 0; j < 4; ++j) acc2[i][j] = 0.f;
    for (int k = 0; k < 64; k += 4) {
        float av[4][4];
        #pragma unroll
        for (int i = 0; i < 4; ++i) {
            const float4 v = *reinterpret_cast<const float4*>(xs + (r0 + i) * 68 + k);
            av[i][0] = v.x; av[i][1] = v.y; av[i][2] = v.z; av[i][3] = v.w;
        }
        #pragma unroll
        for (int kk = 0; kk < 4; ++kk) {
            const float4 w = *reinterpret_cast<const float4*>(ws + (k + kk) * 68 + j2);
            const float wv[4] = {w.x, w.y, w.z, w.w};
            #pragma unroll
            for (int i = 0; i < 4; ++i)
                #pragma unroll
                for (int j = 0; j < 4; ++j)
                    acc2[i][j] = fmaf(av[i][kk], wv[j], acc2[i][j]);
        }
    }
    const float4 bb2 = *reinterpret_cast<const float4*>(b2 + j2);
    __syncthreads();
    #pragma unroll
    for (int i = 0; i < 4; ++i) {
        float4 v;
        v.x = fmaxf(acc2[i][0] + bb2.x, 0.f);
        v.y = fmaxf(acc2[i][1] + bb2.y, 0.f);
        v.z = fmaxf(acc2[i][2] + bb2.z, 0.f);
        v.w = fmaxf(acc2[i][3] + bb2.w, 0.f);
        *reinterpret_cast<float4*>(xs + (r0 + i) * 68 + j2) = v;   // y2 -> xs
    }
    __syncthreads();

    // layer 3: out[r] = y2[r] @ W3 + b3  (64 -> 2); one wave-pair per 16 rows
    // thread t handles row rr = t>>2, quarter qq = t&3 (16 channels each)
    const int rr = t >> 2, qq = t & 3;
    float p0 = 0.f, p1 = 0.f;
    #pragma unroll
    for (int c = 0; c < 16; ++c) {
        const float y = xs[rr * 68 + qq * 16 + c];
        p0 = fmaf(y, W3[(qq * 16 + c) * 2 + 0], p0);
        p1 = fmaf(y, W3[(qq * 16 + c) * 2 + 1], p1);
    }
    #pragma unroll
    for (int o = 1; o <= 2; o <<= 1) {
        p0 += __shfl_xor(p0, o);
        p1 += __shfl_xor(p1, o);
    }
    if (qq == 0 && rr < nvalid) {
        float2 st; st.x = p0 + b3[0]; st.y = p1 + b3[1];
        *reinterpret_cast<float2*>(out + (size_t)(base + rr) * 2) = st;
    }
}

extern "C" void kernel_launch(void* const* d_in, const int* in_sizes, int n_in,
                              void* d_out, int out_size, void* d_ws, size_t ws_size,
                              hipStream_t stream)
{
    const float* x     = (const float*)d_in[0];
    const int*   ei    = (const int*)d_in[1];
    const float* c1W1  = (const float*)d_in[2];
    const float* c1b1  = (const float*)d_in[3];
    const float* c1lnw = (const float*)d_in[4];
    const float* c1lnb = (const float*)d_in[5];
    const float* c1W2  = (const float*)d_in[6];
    const float* c1b2  = (const float*)d_in[7];
    const float* n1w   = (const float*)d_in[8];
    const float* n1b   = (const float*)d_in[9];
    const float* cW1   = (const float*)d_in[10];
    const float* cb1   = (const float*)d_in[11];
    const float* clnw  = (const float*)d_in[12];
    const float* clnb  = (const float*)d_in[13];
    const float* cW2   = (const float*)d_in[14];
    const float* cb2   = (const float*)d_in[15];
    const float* nw    = (const float*)d_in[16];
    const float* nb    = (const float*)d_in[17];
    const float* lW1   = (const float*)d_in[18];
    const float* lb1   = (const float*)d_in[19];
    const float* lW2   = (const float*)d_in[20];
    const float* lb2   = (const float*)d_in[21];
    const float* lW3   = (const float*)d_in[22];
    const float* lb3   = (const float*)d_in[23];
    float* out = (float*)d_out;

    float* bufA = (float*)d_ws;
    float* bufB = bufA + NC;
    float* hbuf = bufB + NC;
    int* cursor = (int*)(hbuf + NC);
    int* off    = cursor + NN;
    int* esrc   = off + NN + 2;
    int* part   = esrc + NE;
    double* dsum = (double*)(part + 256);

    hipMemsetAsync(cursor, 0, NN * sizeof(int), stream);
    hipMemsetAsync(dsum, 0, 10 * sizeof(double), stream);
    hist_kernel<<<3125, 256, 0, stream>>>(ei, cursor);
    scan1_kernel<<<SB, 256, 0, stream>>>(cursor, part);
    scan2_kernel<<<1, 128, 0, stream>>>(part, off);
    scan3_kernel<<<SB, 256, 0, stream>>>(part, cursor, off);
    scatter_kernel<<<3125, 256, 0, stream>>>(ei, cursor, esrc);

    const int AGG_BLOCKS = 25000;   // wave per node

    // layer 1 (plain)
    agg_kernel<0><<<AGG_BLOCKS, 256, 0, stream>>>(x, off, esrc, nullptr, nullptr, nullptr, hbuf);
    conv_mlp_kernel<0><<<NT, 256, 0, stream>>>(hbuf, nullptr, c1W1, c1b1, c1lnw, c1lnb,
                                               c1W2, c1b2, bufA, dsum + 0);
    ln_apply_kernel<<<2048, 256, 0, stream>>>(bufA, n1w, n1b, dsum + 0, bufB, dsum + 2);

    // layers 2..4 (res+), ping-pong xc between bufB/bufA
    agg_kernel<1><<<AGG_BLOCKS, 256, 0, stream>>>(bufB, off, esrc, dsum + 2, nw + 0, nb + 0, hbuf);
    conv_mlp_kernel<1><<<NT, 256, 0, stream>>>(hbuf, bufB, cW1 + 0 * 8192, cb1 + 0 * 128,
                                               clnw + 0 * 128, clnb + 0 * 128,
                                               cW2 + 0 * 8192, cb2 + 0 * 64, bufA, dsum + 4);

    agg_kernel<1><<<AGG_BLOCKS, 256, 0, stream>>>(bufA, off, esrc, dsum + 4, nw + 64, nb + 64, hbuf);
    conv_mlp_kernel<1><<<NT, 256, 0, stream>>>(hbuf, bufA, cW1 + 1 * 8192, cb1 + 1 * 128,
                                               clnw + 1 * 128, clnb + 1 * 128,
                                               cW2 + 1 * 8192, cb2 + 1 * 64, bufB, dsum + 6);

    agg_kernel<1><<<AGG_BLOCKS, 256, 0, stream>>>(bufB, off, esrc, dsum + 6, nw + 128, nb + 128, hbuf);
    conv_mlp_kernel<1><<<NT, 256, 0, stream>>>(hbuf, bufB, cW1 + 2 * 8192, cb1 + 2 * 128,
                                               clnw + 2 * 128, clnb + 2 * 128,
                                               cW2 + 2 * 8192, cb2 + 2 * 64, bufA, dsum + 8);

    // dense head
    head_kernel<<<NT, 256, 0, stream>>>(bufA, lW1, lb1, lW2, lb2, lW3, lb3, out);
}